// Round 2
// baseline (1816.177 us; speedup 1.0000x reference)
//
#include <hip/hip_runtime.h>
#include <hip/hip_bf16.h>
#include <math.h>

#define NMSG 16384
#define NNEI 10
#define INF_ 135
#define HID 256
#define NHEADS 4
#define DPH 64
#define DEPTH 5

__device__ __forceinline__ float sigmoidf_(float x){ return 1.f/(1.f+expf(-x)); }

// C[m,j] = EPI( sum_k A[m,k]*W[j,k] + bias[j], E, X1, X2 )
// A: M x K row-major (stride lda). W: 256 x K row-major (stride ldw).
// Output always N x 256 (stride HID).
// EPI 0: store (acc + bias)
// EPI 1: z  = sigmoid(acc + bias + E)
// EPI 2: rs = sigmoid(acc + bias + E) * X1
// EPI 3: hn = ((1-X2)*X1 + X2*tanh(acc+bias+E)) * (m!=0)
template<int EPI>
__global__ __launch_bounds__(256) void gemm_k(
    const float* __restrict__ A, int K, int lda,
    const float* __restrict__ W, int ldw,
    const float* __restrict__ bias,
    const float* __restrict__ E,
    const float* __restrict__ X1,
    const float* __restrict__ X2,
    float* __restrict__ C)
{
    constexpr int BM=64, BN=64, BK=16;
    __shared__ float As[BK][BM];
    __shared__ float Ws[BK][BN];
    const int tid = threadIdx.x;
    const int tx = tid & 15, ty = tid >> 4;
    const int bm0 = blockIdx.x * BM;
    const int bn0 = blockIdx.y * BN;
    float acc[4][4] = {};
    for (int k0 = 0; k0 < K; k0 += BK){
        #pragma unroll
        for (int i = 0; i < 4; ++i){
            int idx = tid + i*256;
            int m = idx >> 4, kk = idx & 15;
            int k = k0 + kk;
            float av = 0.f, wv = 0.f;
            if (k < K){
                av = A[(size_t)(bm0+m)*lda + k];
                wv = W[(size_t)(bn0+m)*ldw + k];
            }
            As[kk][m] = av;
            Ws[kk][m] = wv;
        }
        __syncthreads();
        #pragma unroll
        for (int kk = 0; kk < BK; ++kk){
            const float4 a4 = *reinterpret_cast<const float4*>(&As[kk][ty*4]);
            const float4 b4 = *reinterpret_cast<const float4*>(&Ws[kk][tx*4]);
            const float av[4] = {a4.x, a4.y, a4.z, a4.w};
            const float bv[4] = {b4.x, b4.y, b4.z, b4.w};
            #pragma unroll
            for (int i = 0; i < 4; ++i)
                #pragma unroll
                for (int j = 0; j < 4; ++j)
                    acc[i][j] = fmaf(av[i], bv[j], acc[i][j]);
        }
        __syncthreads();
    }
    #pragma unroll
    for (int i = 0; i < 4; ++i){
        const int m = bm0 + ty*4 + i;
        #pragma unroll
        for (int j = 0; j < 4; ++j){
            const int n = bn0 + tx*4 + j;
            float v = acc[i][j];
            if (bias) v += bias[n];
            const size_t off = (size_t)m*HID + n;
            if constexpr (EPI == 0){
                C[off] = v;
            } else if constexpr (EPI == 1){
                C[off] = sigmoidf_(v + E[off]);
            } else if constexpr (EPI == 2){
                C[off] = sigmoidf_(v + E[off]) * X1[off];
            } else {
                float ph = tanhf(v + E[off]);
                float z = X2[off], sh = X1[off];
                float hn = (1.f - z)*sh + z*ph;
                C[off] = (m == 0) ? 0.f : hn;
            }
        }
    }
}

// Per-message reductions: sk[m,head] = sum_d lrelu(Kmat[m, head*64+d]) * alpha[head*128+aoff+d]
// and (if h != null) S[m] = rowsum(h[m,:]).
__global__ __launch_bounds__(256) void sks_k(
    const float* __restrict__ Kmat,
    const float* __restrict__ h,
    const float* __restrict__ alpha, int aoff,
    float* __restrict__ sk, float* __restrict__ S)
{
    const int gid  = blockIdx.x*256 + threadIdx.x;
    const int m    = gid >> 6;
    const int lane = gid & 63;
    const int head = lane >> 4, sub = lane & 15;
    const float4 kv = *reinterpret_cast<const float4*>(Kmat + (size_t)m*HID + lane*4);
    const float kvv[4] = {kv.x, kv.y, kv.z, kv.w};
    const float* al = alpha + head*2*DPH + aoff + sub*4;
    float p = 0.f;
    #pragma unroll
    for (int t = 0; t < 4; ++t){
        float x = kvv[t];
        float lr = x > 0.f ? x : 0.01f*x;
        p = fmaf(lr, al[t], p);
    }
    p += __shfl_xor(p, 1); p += __shfl_xor(p, 2);
    p += __shfl_xor(p, 4); p += __shfl_xor(p, 8);
    if (sub == 0) sk[m*4 + head] = p;
    if (h){
        const float4 hv = *reinterpret_cast<const float4*>(h + (size_t)m*HID + lane*4);
        float s = hv.x + hv.y + hv.z + hv.w;
        s += __shfl_xor(s, 1);  s += __shfl_xor(s, 2);  s += __shfl_xor(s, 4);
        s += __shfl_xor(s, 8);  s += __shfl_xor(s, 16); s += __shfl_xor(s, 32);
        if (lane == 0) S[m] = s;
    }
}

// Attention: per message n, thread handles 4 contiguous dims (lane*4) of one head.
__global__ __launch_bounds__(256) void attn_k(
    const int*   __restrict__ bgraph,
    const float* __restrict__ sq,
    const float* __restrict__ sk,
    const float* __restrict__ S,
    const float* __restrict__ abias,
    const float* __restrict__ V,
    float* __restrict__ sum_h)
{
    const int gid  = blockIdx.x*256 + threadIdx.x;
    const int n    = gid >> 6;
    const int lane = gid & 63;
    const int head = lane >> 4;
    const float ab  = abias[head];
    const float sqv = sq[n*4 + head];
    int g[NNEI];
    #pragma unroll
    for (int j = 0; j < NNEI; ++j) g[j] = bgraph[n*NNEI + j];
    float sc[NNEI];
    float mx = -1e30f;
    #pragma unroll
    for (int j = 0; j < NNEI; ++j){
        float s = sqv + sk[g[j]*4 + head] + ab;
        if (S[g[j]] == 0.f) s = -1e18f;
        sc[j] = s;
        mx = fmaxf(mx, s);
    }
    float den = 0.f;
    #pragma unroll
    for (int j = 0; j < NNEI; ++j){ sc[j] = expf(sc[j] - mx); den += sc[j]; }
    const float inv = 1.f/den;
    float4 acc = {0.f, 0.f, 0.f, 0.f};
    #pragma unroll
    for (int j = 0; j < NNEI; ++j){
        const float w = sc[j]*inv;
        const float4 vv = *reinterpret_cast<const float4*>(V + (size_t)g[j]*HID + lane*4);
        acc.x = fmaf(w, vv.x, acc.x);
        acc.y = fmaf(w, vv.y, acc.y);
        acc.z = fmaf(w, vv.z, acc.z);
        acc.w = fmaf(w, vv.w, acc.w);
    }
    *reinterpret_cast<float4*>(sum_h + (size_t)n*HID + lane*4) = acc;
}

extern "C" void kernel_launch(void* const* d_in, const int* in_sizes, int n_in,
                              void* d_out, int out_size, void* d_ws, size_t ws_size,
                              hipStream_t stream) {
    const float* fmess = (const float*)d_in[0];
    const int*   bgraph= (const int*  )d_in[1];
    const float* Wq    = (const float*)d_in[2];
    const float* bq    = (const float*)d_in[3];
    const float* Wk    = (const float*)d_in[4];
    const float* bk    = (const float*)d_in[5];
    const float* Wv    = (const float*)d_in[6];
    const float* bv    = (const float*)d_in[7];
    const float* alpha = (const float*)d_in[8];
    const float* abias = (const float*)d_in[9];
    const float* Wz    = (const float*)d_in[10];
    const float* bz    = (const float*)d_in[11];
    const float* Wr    = (const float*)d_in[12];
    const float* Ur    = (const float*)d_in[13];
    const float* bur   = (const float*)d_in[14];
    const float* Wh    = (const float*)d_in[15];
    const float* bh    = (const float*)d_in[16];
    float* out = (float*)d_out;

    float* ws = (float*)d_ws;
    const size_t NH = (size_t)NMSG*HID;
    float* h    = ws;
    float* Kb   = ws + 1*NH;   // also q (precompute) and rs (per-step) alias
    float* Vb   = ws + 2*NH;
    float* sumh = ws + 3*NH;
    float* zb   = ws + 4*NH;
    float* Fz   = ws + 5*NH;
    float* Fr   = ws + 6*NH;
    float* Fh   = ws + 7*NH;
    float* sq   = ws + 8*NH;
    float* sk   = sq + 4*NMSG;
    float* Sb   = sk + 4*NMSG;
    float* rs   = Kb;

    const dim3 gg(NMSG/64, HID/64);
    const dim3 gb(256);
    const int rgrid = NMSG*64/256;

    hipMemsetAsync(h, 0, NH*sizeof(float), stream);

    // ---- precompute (loop-invariant) ----
    // q = fmess @ Wq.T + bq  -> Kb ; then sq
    gemm_k<0><<<gg,gb,0,stream>>>(fmess, INF_, INF_, Wq, INF_, bq, nullptr,nullptr,nullptr, Kb);
    sks_k<<<rgrid,gb,0,stream>>>(Kb, nullptr, alpha, 0, sq, nullptr);
    // Fz = fmess @ Wz[:, :135].T ; Fr = fmess @ Wr.T ; Fh = fmess @ Wh[:, :135].T
    gemm_k<0><<<gg,gb,0,stream>>>(fmess, INF_, INF_, Wz, INF_+HID, nullptr, nullptr,nullptr,nullptr, Fz);
    gemm_k<0><<<gg,gb,0,stream>>>(fmess, INF_, INF_, Wr, INF_,     nullptr, nullptr,nullptr,nullptr, Fr);
    gemm_k<0><<<gg,gb,0,stream>>>(fmess, INF_, INF_, Wh, INF_+HID, nullptr, nullptr,nullptr,nullptr, Fh);

    // ---- recurrence ----
    for (int step = 0; step < DEPTH; ++step){
        float* hout = (step == DEPTH-1) ? out : h;
        // K, V per message
        gemm_k<0><<<gg,gb,0,stream>>>(h, HID, HID, Wk, HID, bk, nullptr,nullptr,nullptr, Kb);
        gemm_k<0><<<gg,gb,0,stream>>>(h, HID, HID, Wv, HID, bv, nullptr,nullptr,nullptr, Vb);
        // sk scalars + mask rowsums
        sks_k<<<rgrid,gb,0,stream>>>(Kb, h, alpha, DPH, sk, Sb);
        // attention -> sum_h
        attn_k<<<rgrid,gb,0,stream>>>(bgraph, sq, sk, Sb, abias, Vb, sumh);
        // z = sigmoid(Fz + sumh@Wz2.T + bz)
        gemm_k<1><<<gg,gb,0,stream>>>(sumh, HID, HID, Wz+INF_, INF_+HID, bz, Fz, nullptr, nullptr, zb);
        // rs = sigmoid(Fr + sumh@Ur.T + bur) * sumh
        gemm_k<2><<<gg,gb,0,stream>>>(sumh, HID, HID, Ur, HID, bur, Fr, sumh, nullptr, rs);
        // hnew = ((1-z)*sumh + z*tanh(Fh + rs@Wh2.T + bh)) * mask
        gemm_k<3><<<gg,gb,0,stream>>>(rs, HID, HID, Wh+INF_, INF_+HID, bh, Fh, sumh, zb, hout);
    }
}

// Round 4
// 637.527 us; speedup vs baseline: 2.8488x; 2.8488x over previous
//
#include <hip/hip_runtime.h>
#include <hip/hip_bf16.h>
#include <math.h>

#define NMSG 16384
#define NNEI 10
#define INF_ 135
#define KPAD 160
#define HID 256
#define DPH 64
#define DEPTH 5

typedef __attribute__((ext_vector_type(8))) short short8b;
typedef __attribute__((ext_vector_type(4))) float f32x4;
typedef __hip_bfloat16 bf16;

__device__ __forceinline__ float sigmoidf_(float x){ return 1.f/(1.f+expf(-x)); }
__device__ __forceinline__ float b2f(unsigned short u){ return __uint_as_float(((unsigned)u)<<16); }

__device__ __forceinline__ void gload_lds16(const void* g, void* l){
    __builtin_amdgcn_global_load_lds(
        (const __attribute__((address_space(1))) unsigned int*)g,
        (__attribute__((address_space(3))) unsigned int*)l, 16, 0, 0);
}

// C = A @ B^T.  A: [M][K] bf16 row-major (lda=K).  B: [N][K] bf16 row-major (weight rows).
// 128x128 tile, BK=32, 4 waves -> 64x64 per wave, mfma 16x16x32 bf16.
// EPI 0: PRE  -> n>>8 selects {Cf(Q,fp32), Cb0(FZ), Cb1(FR), Cb2(FH)} each [M][256]
// EPI 1: KV   -> Cb0 bf16 [M][512]
// EPI 2: ZR   -> n<256: Cf=sigmoid(acc+E0+b0) (zb fp32); else Cb0=bf16(sigmoid(acc+E1+b1)*SH) (rs)
// EPI 3: H    -> ph=tanh(acc+E0+b0); hn=((1-ZB)*SH+ZB*ph)*(m!=0); Cf=hn fp32; Cb0=bf16(hn)
template<int EPI>
__global__ __launch_bounds__(256) void mm_k(
    const bf16* __restrict__ A, const bf16* __restrict__ B, int K,
    float* __restrict__ Cf,
    bf16* __restrict__ Cb0, bf16* __restrict__ Cb1, bf16* __restrict__ Cb2,
    const bf16* __restrict__ E0, const bf16* __restrict__ E1,
    const float* __restrict__ b0, const float* __restrict__ b1,
    const float* __restrict__ SH, const float* __restrict__ ZB)
{
    constexpr int BM=128, BK=32;
    __shared__ __align__(16) unsigned short As[BM*BK];
    __shared__ __align__(16) unsigned short Bs[BM*BK];
    const int tid  = threadIdx.x;
    const int wave = tid >> 6, lane = tid & 63;
    const int bm0  = blockIdx.x * BM, bn0 = blockIdx.y * BM;
    const int wr = wave >> 1, wc = wave & 1;
    const int rA = lane >> 2, slot = lane & 3;
    const int fr = lane & 15, fs = lane >> 4;

    f32x4 acc[4][4] = {};

    for (int k0 = 0; k0 < K; k0 += BK){
        #pragma unroll
        for (int i = 0; i < 2; ++i){
            const int r0 = (wave*2 + i) * 16;
            const int r  = r0 + rA;
            const int sw = slot ^ ((r >> 1) & 3);
            // linear LDS dest (base+lane*16), inverse-swizzled global source
            gload_lds16(A + (size_t)(bm0 + r)*K + k0 + sw*8, As + r0*BK);
            gload_lds16(B + (size_t)(bn0 + r)*K + k0 + sw*8, Bs + r0*BK);
        }
        __syncthreads();
        short8b af[4], bfr[4];
        #pragma unroll
        for (int mi = 0; mi < 4; ++mi){
            const int row = wr*64 + mi*16 + fr;
            const int sw = fs ^ ((row >> 1) & 3);
            af[mi] = *(const short8b*)((const char*)As + row*64 + sw*16);
        }
        #pragma unroll
        for (int ni = 0; ni < 4; ++ni){
            const int row = wc*64 + ni*16 + fr;
            const int sw = fs ^ ((row >> 1) & 3);
            bfr[ni] = *(const short8b*)((const char*)Bs + row*64 + sw*16);
        }
        #pragma unroll
        for (int mi = 0; mi < 4; ++mi)
            #pragma unroll
            for (int ni = 0; ni < 4; ++ni)
                acc[mi][ni] = __builtin_amdgcn_mfma_f32_16x16x32_bf16(af[mi], bfr[ni], acc[mi][ni], 0, 0, 0);
        __syncthreads();
    }

    // C/D layout: col = lane&15, row = (lane>>4)*4 + t   [m89-verified]
    #pragma unroll
    for (int mi = 0; mi < 4; ++mi){
        #pragma unroll
        for (int ni = 0; ni < 4; ++ni){
            #pragma unroll
            for (int t = 0; t < 4; ++t){
                const int m = bm0 + wr*64 + mi*16 + fs*4 + t;
                const int n = bn0 + wc*64 + ni*16 + fr;
                const float v = acc[mi][ni][t];
                if constexpr (EPI == 0){
                    const int sel = n >> 8, c = n & 255;
                    const size_t off = (size_t)m*HID + c;
                    if      (sel == 0) Cf[off]  = v;
                    else if (sel == 1) Cb0[off] = __float2bfloat16(v);
                    else if (sel == 2) Cb1[off] = __float2bfloat16(v);
                    else               Cb2[off] = __float2bfloat16(v);
                } else if constexpr (EPI == 1){
                    Cb0[(size_t)m*512 + n] = __float2bfloat16(v);
                } else if constexpr (EPI == 2){
                    const int c = n & 255;
                    const size_t off = (size_t)m*HID + c;
                    if (n < 256){
                        Cf[off] = sigmoidf_(v + b2f(*(const unsigned short*)&E0[off]) + b0[c]);
                    } else {
                        float r = sigmoidf_(v + b2f(*(const unsigned short*)&E1[off]) + b1[c]);
                        Cb0[off] = __float2bfloat16(r * SH[off]);
                    }
                } else {
                    const size_t off = (size_t)m*HID + n;
                    const float ph = tanhf(v + b2f(*(const unsigned short*)&E0[off]) + b0[n]);
                    const float z = ZB[off], sh = SH[off];
                    float hn = (1.f - z)*sh + z*ph;
                    if (m == 0) hn = 0.f;
                    Cf[off] = hn;
                    Cb0[off] = __float2bfloat16(hn);
                }
            }
        }
    }
}

// fp32 [nrows][srcld] (cols col0..col0+ncols) -> bf16 [nrows][dstld], zero-padded
__global__ __launch_bounds__(256) void conv_k(
    const float* __restrict__ src, int srcld, int col0, int ncols,
    bf16* __restrict__ dst, int dstld, int total)
{
    int i = blockIdx.x*256 + threadIdx.x;
    if (i >= total) return;
    int r = i / dstld, c = i - r*dstld;
    float v = (c < ncols) ? src[(size_t)r*srcld + col0 + c] : 0.f;
    dst[i] = __float2bfloat16(v);
}

// sk[m,head] = sum_d lrelu(K[m,d]+kb[d]) * alpha[head*128+aoff+d%64]; optional S[m]=rowsum(h[m])
template<typename T>
__global__ __launch_bounds__(256) void sks_k(
    const T* __restrict__ Kmat, int ldk, const float* __restrict__ kb,
    const float* __restrict__ h,
    const float* __restrict__ alpha, int aoff,
    float* __restrict__ sk, float* __restrict__ S)
{
    const int gid  = blockIdx.x*256 + threadIdx.x;
    const int m    = gid >> 6;
    const int lane = gid & 63;
    const int head = lane >> 4, sub = lane & 15;
    float kv[4];
    if constexpr (sizeof(T) == 4){
        const float4 t = *reinterpret_cast<const float4*>(Kmat + (size_t)m*ldk + lane*4);
        kv[0]=t.x; kv[1]=t.y; kv[2]=t.z; kv[3]=t.w;
    } else {
        const ushort4 t = *reinterpret_cast<const ushort4*>(
            (const unsigned short*)Kmat + (size_t)m*ldk + lane*4);
        kv[0]=b2f(t.x); kv[1]=b2f(t.y); kv[2]=b2f(t.z); kv[3]=b2f(t.w);
    }
    const float4 bb = *reinterpret_cast<const float4*>(kb + lane*4);
    const float bbv[4] = {bb.x, bb.y, bb.z, bb.w};
    const float* al = alpha + head*2*DPH + aoff + sub*4;
    float p = 0.f;
    #pragma unroll
    for (int t = 0; t < 4; ++t){
        float x = kv[t] + bbv[t];
        float lr = x > 0.f ? x : 0.01f*x;
        p = fmaf(lr, al[t], p);
    }
    p += __shfl_xor(p, 1); p += __shfl_xor(p, 2);
    p += __shfl_xor(p, 4); p += __shfl_xor(p, 8);
    if (sub == 0) sk[m*4 + head] = p;
    if (h){
        const float4 hv = *reinterpret_cast<const float4*>(h + (size_t)m*HID + lane*4);
        float s = hv.x + hv.y + hv.z + hv.w;
        s += __shfl_xor(s, 1);  s += __shfl_xor(s, 2);  s += __shfl_xor(s, 4);
        s += __shfl_xor(s, 8);  s += __shfl_xor(s, 16); s += __shfl_xor(s, 32);
        if (lane == 0) S[m] = s;
    }
}

// attention: per message n, lane handles 4 dims of one head. V bf16 (stride ldv), +bv post-softmax.
__global__ __launch_bounds__(256) void attn_k(
    const int*   __restrict__ bgraph,
    const float* __restrict__ sq,
    const float* __restrict__ sk,
    const float* __restrict__ S,
    const float* __restrict__ abias,
    const bf16*  __restrict__ V, int ldv,
    const float* __restrict__ bv,
    float* __restrict__ sumh, bf16* __restrict__ sumhb)
{
    const int gid  = blockIdx.x*256 + threadIdx.x;
    const int n    = gid >> 6;
    const int lane = gid & 63;
    const int head = lane >> 4;
    const float ab  = abias[head];
    const float sqv = sq[n*4 + head];
    int g[NNEI];
    #pragma unroll
    for (int j = 0; j < NNEI; ++j) g[j] = bgraph[n*NNEI + j];
    float sc[NNEI];
    float mx = -1e30f;
    #pragma unroll
    for (int j = 0; j < NNEI; ++j){
        float s = sqv + sk[g[j]*4 + head] + ab;
        if (S[g[j]] == 0.f) s = -1e18f;
        sc[j] = s;
        mx = fmaxf(mx, s);
    }
    float den = 0.f;
    #pragma unroll
    for (int j = 0; j < NNEI; ++j){ sc[j] = expf(sc[j] - mx); den += sc[j]; }
    const float inv = 1.f/den;
    float a0=0.f, a1=0.f, a2=0.f, a3=0.f;
    #pragma unroll
    for (int j = 0; j < NNEI; ++j){
        const float w = sc[j]*inv;
        const ushort4 vv = *reinterpret_cast<const ushort4*>(
            (const unsigned short*)V + (size_t)g[j]*ldv + lane*4);
        a0 = fmaf(w, b2f(vv.x), a0);
        a1 = fmaf(w, b2f(vv.y), a1);
        a2 = fmaf(w, b2f(vv.z), a2);
        a3 = fmaf(w, b2f(vv.w), a3);
    }
    const float4 bvv = *reinterpret_cast<const float4*>(bv + lane*4);
    a0 += bvv.x; a1 += bvv.y; a2 += bvv.z; a3 += bvv.w;
    const size_t off = (size_t)n*HID + lane*4;
    *reinterpret_cast<float4*>(sumh + off) = make_float4(a0, a1, a2, a3);
    bf16* ob = sumhb + off;
    ob[0]=__float2bfloat16(a0); ob[1]=__float2bfloat16(a1);
    ob[2]=__float2bfloat16(a2); ob[3]=__float2bfloat16(a3);
}

extern "C" void kernel_launch(void* const* d_in, const int* in_sizes, int n_in,
                              void* d_out, int out_size, void* d_ws, size_t ws_size,
                              hipStream_t stream) {
    const float* fmess = (const float*)d_in[0];
    const int*   bgraph= (const int*  )d_in[1];
    const float* Wq    = (const float*)d_in[2];
    const float* bq    = (const float*)d_in[3];
    const float* Wk    = (const float*)d_in[4];
    const float* bk    = (const float*)d_in[5];
    const float* Wv    = (const float*)d_in[6];
    const float* bv    = (const float*)d_in[7];
    const float* alpha = (const float*)d_in[8];
    const float* abias = (const float*)d_in[9];
    const float* Wz    = (const float*)d_in[10];
    const float* bz    = (const float*)d_in[11];
    const float* Wr    = (const float*)d_in[12];
    const float* Ur    = (const float*)d_in[13];
    const float* bur   = (const float*)d_in[14];
    const float* Wh    = (const float*)d_in[15];
    const float* bh    = (const float*)d_in[16];
    float* out = (float*)d_out;

    const size_t NH = (size_t)NMSG*HID;
    char* p = (char*)d_ws;
    auto alloc = [&](size_t bytes)->char*{ char* r = p; p += (bytes + 255) & ~(size_t)255; return r; };
    bf16* fmessb = (bf16*)alloc((size_t)NMSG*KPAD*2);
    bf16* Wcat   = (bf16*)alloc((size_t)1024*KPAD*2);
    bf16* WKV    = (bf16*)alloc((size_t)512*HID*2);
    bf16* WZR    = (bf16*)alloc((size_t)512*HID*2);
    bf16* WH     = (bf16*)alloc((size_t)256*HID*2);
    float* Q     = (float*)alloc(NH*4);          // aliased by zb in-loop
    bf16* FZb    = (bf16*)alloc(NH*2);
    bf16* FRb    = (bf16*)alloc(NH*2);
    bf16* FHb    = (bf16*)alloc(NH*2);
    bf16* KVb    = (bf16*)alloc(NH*2*2);         // [N][512]
    float* h     = (float*)alloc(NH*4);
    bf16* hb     = (bf16*)alloc(NH*2);
    float* sumh  = (float*)alloc(NH*4);
    bf16* sumhb  = (bf16*)alloc(NH*2);
    bf16* rsb    = (bf16*)alloc(NH*2);
    float* sq    = (float*)alloc((size_t)NMSG*4*4);
    float* sk    = (float*)alloc((size_t)NMSG*4*4);
    float* S     = (float*)alloc((size_t)NMSG*4);
    float* zb    = Q;

    const dim3 gb(256);
    const int rgrid = NMSG*64/256;

    // ---- weight/input conversions (must run every call; inputs are re-poisoned) ----
    {
        int tot = NMSG*KPAD;
        conv_k<<<(tot+255)/256, gb, 0, stream>>>(fmess, INF_, 0, INF_, fmessb, KPAD, tot);
        int wt = 256*KPAD;
        conv_k<<<(wt+255)/256, gb, 0, stream>>>(Wq, INF_,      0, INF_, Wcat + 0*(size_t)256*KPAD, KPAD, wt);
        conv_k<<<(wt+255)/256, gb, 0, stream>>>(Wz, INF_+HID,  0, INF_, Wcat + 1*(size_t)256*KPAD, KPAD, wt);
        conv_k<<<(wt+255)/256, gb, 0, stream>>>(Wr, INF_,      0, INF_, Wcat + 2*(size_t)256*KPAD, KPAD, wt);
        conv_k<<<(wt+255)/256, gb, 0, stream>>>(Wh, INF_+HID,  0, INF_, Wcat + 3*(size_t)256*KPAD, KPAD, wt);
        int wh = 256*HID;
        conv_k<<<(wh+255)/256, gb, 0, stream>>>(Wk, HID,       0, HID,  WKV,             HID, wh);
        conv_k<<<(wh+255)/256, gb, 0, stream>>>(Wv, HID,       0, HID,  WKV + (size_t)256*HID, HID, wh);
        conv_k<<<(wh+255)/256, gb, 0, stream>>>(Wz, INF_+HID, INF_, HID, WZR,            HID, wh);
        conv_k<<<(wh+255)/256, gb, 0, stream>>>(Ur, HID,       0, HID,  WZR + (size_t)256*HID, HID, wh);
        conv_k<<<(wh+255)/256, gb, 0, stream>>>(Wh, INF_+HID, INF_, HID, WH,             HID, wh);
    }
    hipMemsetAsync(h,  0, NH*4, stream);
    hipMemsetAsync(hb, 0, NH*2, stream);

    // ---- precompute: [q|Fz|Fr|Fh] = fmess_bf16 @ Wcat^T (K=160) ----
    mm_k<0><<<dim3(NMSG/128, 8), gb, 0, stream>>>(fmessb, Wcat, KPAD,
        Q, FZb, FRb, FHb, nullptr, nullptr, nullptr, nullptr, nullptr, nullptr);
    sks_k<float><<<rgrid, gb, 0, stream>>>(Q, HID, bq, nullptr, alpha, 0, sq, nullptr);

    // ---- recurrence ----
    for (int step = 0; step < DEPTH; ++step){
        float* hout = (step == DEPTH-1) ? out : h;
        mm_k<1><<<dim3(NMSG/128, 4), gb, 0, stream>>>(hb, WKV, HID,
            nullptr, KVb, nullptr, nullptr, nullptr, nullptr, nullptr, nullptr, nullptr, nullptr);
        sks_k<bf16><<<rgrid, gb, 0, stream>>>(KVb, 512, bk, h, alpha, DPH, sk, S);
        attn_k<<<rgrid, gb, 0, stream>>>(bgraph, sq, sk, S, abias, KVb + 256, 512, bv, sumh, sumhb);
        mm_k<2><<<dim3(NMSG/128, 4), gb, 0, stream>>>(sumhb, WZR, HID,
            zb, rsb, nullptr, nullptr, FZb, FRb, bz, bur, sumh, nullptr);
        mm_k<3><<<dim3(NMSG/128, 2), gb, 0, stream>>>(rsb, WH, HID,
            hout, hb, nullptr, nullptr, FHb, nullptr, bh, nullptr, sumh, zb);
    }
}